// Round 4
// baseline (204.353 us; speedup 1.0000x reference)
//
#include <hip/hip_runtime.h>

typedef unsigned int u32;
typedef _Float16 f16;
typedef _Float16 f16x8 __attribute__((ext_vector_type(8)));
typedef _Float16 f16x4 __attribute__((ext_vector_type(4)));
typedef float f32x4 __attribute__((ext_vector_type(4)));

#define LOG2E 1.4426950408889634f

__device__ __forceinline__ void gl_lds16(const void* g, void* l) {
  // async global->LDS, 16B per lane; LDS dest = wave-uniform base + lane*16
  __builtin_amdgcn_global_load_lds(
      (const __attribute__((address_space(1))) u32*)g,
      (__attribute__((address_space(3))) u32*)l, 16, 0, 0);
}

__device__ __forceinline__ f32x4 mfma16(f16x8 a, f16x8 b, f32x4 c) {
  return __builtin_amdgcn_mfma_f32_16x16x32_f16(a, b, c, 0, 0, 0);
}

// ---------------- fp32 -> fp16 convert (vectorized) ----------------
__global__ void k_cvt(const float* __restrict__ in, f16* __restrict__ out, int n4) {
  int stride = gridDim.x * blockDim.x;
  for (int i = blockIdx.x * blockDim.x + threadIdx.x; i < n4; i += stride) {
    f32x4 v = *(const f32x4*)(in + (size_t)i * 4);
    f16x4 o;
    o[0] = (f16)v[0]; o[1] = (f16)v[1]; o[2] = (f16)v[2]; o[3] = (f16)v[3];
    *(f16x4*)(out + (size_t)i * 4) = o;
  }
}

// ------------- transpose + convert: in fp32 [R][C] -> out f16 [C][R] -------------
__global__ void k_tconv(const float* __restrict__ in, f16* __restrict__ out, int R, int C) {
  __shared__ f16 tile[32][33];
  int c0 = blockIdx.x * 32, r0 = blockIdx.y * 32;
  int tx = threadIdx.x, ty = threadIdx.y;
#pragma unroll
  for (int i = ty; i < 32; i += 8)
    tile[i][tx] = (f16)in[(size_t)(r0 + i) * C + c0 + tx];
  __syncthreads();
#pragma unroll
  for (int i = ty; i < 32; i += 8)
    out[(size_t)(c0 + i) * R + r0 + tx] = tile[tx][i];
}

// ================= pipelined GEMM core (T3+T4+T5) =================
// BM=128, BN=256, BK=32, 512 threads (8 waves 2x4), per-wave 64x64 out.
// 3 LDS buffers; stage(t+2) while computing t; gate = vmcnt(3) + raw s_barrier
// (tile t+1's loads guaranteed landed, t+2's stay in flight - never drain to 0).

// ---------------- QKV projection GEMM (pipelined) ----------------
// A f16 [8192][1024], Bt f16 [3072][1024] K-major, bias fp32[3072].
// Epilogue scatters q (pre-scaled by 0.125*log2e), k, and v-transposed.
__global__ __launch_bounds__(512, 4) void k_gemm_qkv2(
    const f16* __restrict__ A, const f16* __restrict__ Bt,
    const float* __restrict__ bias,
    f16* __restrict__ qo, f16* __restrict__ ko2, f16* __restrict__ vto) {
  constexpr int NT = 32;  // K/BK = 1024/32
  __shared__ __align__(16) f16 As[3 * 128 * 32];
  __shared__ __align__(16) f16 Bs[3 * 256 * 32];
  const int bn = blockIdx.x * 256, bm = blockIdx.y * 128;
  const int t = threadIdx.x, lane = t & 63, w = t >> 6;
  const int wr = w >> 2, wc = w & 3;
  const int g = lane >> 4, rl = lane & 15;
  const int lr = lane >> 2, lp = lane & 3;

  // staging sources (pre-swizzled so linear LDS dest + swizzled read line up)
  const int arow = w * 16 + lr;
  const f16* aSrc = A + (size_t)(bm + arow) * 1024 + (lp ^ ((arow >> 1) & 3)) * 8;
  const int brow0 = w * 32 + lr, brow1 = brow0 + 16;
  const f16* bSrc0 = Bt + (size_t)(bn + brow0) * 1024 + (lp ^ ((brow0 >> 1) & 3)) * 8;
  const f16* bSrc1 = Bt + (size_t)(bn + brow1) * 1024 + (lp ^ ((brow1 >> 1) & 3)) * 8;
  f16* aDst = As + w * 512;    // + buf*4096
  f16* bDst0 = Bs + w * 1024;  // + buf*8192
  f16* bDst1 = bDst0 + 512;

  f32x4 acc[4][4] = {};

  // prologue: stage tiles 0 (buf0) and 1 (buf1)
  gl_lds16(aSrc, aDst);
  gl_lds16(bSrc0, bDst0);
  gl_lds16(bSrc1, bDst1);
  gl_lds16(aSrc + 32, aDst + 4096);
  gl_lds16(bSrc0 + 32, bDst0 + 8192);
  gl_lds16(bSrc1 + 32, bDst1 + 8192);

  int c = 0, cs = 2;
#pragma unroll 1
  for (int kt = 0; kt < NT; ++kt) {
    // gate: tile kt's stage landed (own loads) -> barrier makes it collective;
    // also all waves' reads of buf cs (last used at kt-1) are complete.
    if (kt + 1 < NT) { asm volatile("s_waitcnt vmcnt(3)" ::: "memory"); }
    else             { asm volatile("s_waitcnt vmcnt(0)" ::: "memory"); }
    __builtin_amdgcn_sched_barrier(0);
    __builtin_amdgcn_s_barrier();
    __builtin_amdgcn_sched_barrier(0);

    if (kt + 2 < NT) {  // stage tile kt+2 into freed buffer
      const int ko = (kt + 2) * 32;
      gl_lds16(aSrc + ko, aDst + cs * 4096);
      gl_lds16(bSrc0 + ko, bDst0 + cs * 8192);
      gl_lds16(bSrc1 + ko, bDst1 + cs * 8192);
    }

    const f16* Ab = As + c * 4096;
    const f16* Bb = Bs + c * 8192;
    f16x8 af[4], bf[4];
#pragma unroll
    for (int i = 0; i < 4; ++i) {
      const int r = wr * 64 + i * 16 + rl;
      af[i] = *(const f16x8*)(Ab + r * 32 + ((g ^ ((r >> 1) & 3)) * 8));
    }
#pragma unroll
    for (int j = 0; j < 4; ++j) {
      const int rb = wc * 64 + j * 16 + rl;
      bf[j] = *(const f16x8*)(Bb + rb * 32 + ((g ^ ((rb >> 1) & 3)) * 8));
    }
    __builtin_amdgcn_s_setprio(1);
#pragma unroll
    for (int i = 0; i < 4; ++i)
#pragma unroll
      for (int j = 0; j < 4; ++j)
        acc[i][j] = mfma16(af[i], bf[j], acc[i][j]);
    __builtin_amdgcn_s_setprio(0);
    __builtin_amdgcn_sched_barrier(0);

    c = (c == 2) ? 0 : c + 1;
    cs = (cs == 2) ? 0 : cs + 1;
  }

  // epilogue: C row=(lane>>4)*4+reg, col=lane&15; scatter q/k/v
#pragma unroll
  for (int i = 0; i < 4; ++i)
#pragma unroll
    for (int j = 0; j < 4; ++j)
#pragma unroll
      for (int r = 0; r < 4; ++r) {
        int m = bm + wr * 64 + i * 16 + g * 4 + r;
        int n = bn + wc * 64 + j * 16 + rl;
        float v = acc[i][j][r] + bias[n];
        int b = m >> 11, s = m & 2047;
        int h = n / 192, rem = n - h * 192;
        int tsel = rem >> 6, d = rem & 63;
        size_t bh = (size_t)(b * 16 + h);
        if (tsel == 0)      qo[(bh * 2048 + s) * 64 + d] = (f16)(v * (0.125f * LOG2E));
        else if (tsel == 1) ko2[(bh * 2048 + s) * 64 + d] = (f16)v;
        else                vto[(bh * 64 + d) * 2048 + s] = (f16)v;  // V transposed
      }
}

// ---------------- output projection GEMM (pipelined) ----------------
// A f16 [8192][1024], Bt f16 [1024][1024] K-major, out fp32 [8192][1024] + bias
__global__ __launch_bounds__(512, 4) void k_gemm_out2(
    const f16* __restrict__ A, const f16* __restrict__ Bt,
    const float* __restrict__ bias, float* __restrict__ out) {
  constexpr int NT = 32;
  __shared__ __align__(16) f16 As[3 * 128 * 32];
  __shared__ __align__(16) f16 Bs[3 * 256 * 32];
  const int bn = blockIdx.x * 256, bm = blockIdx.y * 128;
  const int t = threadIdx.x, lane = t & 63, w = t >> 6;
  const int wr = w >> 2, wc = w & 3;
  const int g = lane >> 4, rl = lane & 15;
  const int lr = lane >> 2, lp = lane & 3;

  const int arow = w * 16 + lr;
  const f16* aSrc = A + (size_t)(bm + arow) * 1024 + (lp ^ ((arow >> 1) & 3)) * 8;
  const int brow0 = w * 32 + lr, brow1 = brow0 + 16;
  const f16* bSrc0 = Bt + (size_t)(bn + brow0) * 1024 + (lp ^ ((brow0 >> 1) & 3)) * 8;
  const f16* bSrc1 = Bt + (size_t)(bn + brow1) * 1024 + (lp ^ ((brow1 >> 1) & 3)) * 8;
  f16* aDst = As + w * 512;
  f16* bDst0 = Bs + w * 1024;
  f16* bDst1 = bDst0 + 512;

  f32x4 acc[4][4] = {};

  gl_lds16(aSrc, aDst);
  gl_lds16(bSrc0, bDst0);
  gl_lds16(bSrc1, bDst1);
  gl_lds16(aSrc + 32, aDst + 4096);
  gl_lds16(bSrc0 + 32, bDst0 + 8192);
  gl_lds16(bSrc1 + 32, bDst1 + 8192);

  int c = 0, cs = 2;
#pragma unroll 1
  for (int kt = 0; kt < NT; ++kt) {
    if (kt + 1 < NT) { asm volatile("s_waitcnt vmcnt(3)" ::: "memory"); }
    else             { asm volatile("s_waitcnt vmcnt(0)" ::: "memory"); }
    __builtin_amdgcn_sched_barrier(0);
    __builtin_amdgcn_s_barrier();
    __builtin_amdgcn_sched_barrier(0);

    if (kt + 2 < NT) {
      const int ko = (kt + 2) * 32;
      gl_lds16(aSrc + ko, aDst + cs * 4096);
      gl_lds16(bSrc0 + ko, bDst0 + cs * 8192);
      gl_lds16(bSrc1 + ko, bDst1 + cs * 8192);
    }

    const f16* Ab = As + c * 4096;
    const f16* Bb = Bs + c * 8192;
    f16x8 af[4], bf[4];
#pragma unroll
    for (int i = 0; i < 4; ++i) {
      const int r = wr * 64 + i * 16 + rl;
      af[i] = *(const f16x8*)(Ab + r * 32 + ((g ^ ((r >> 1) & 3)) * 8));
    }
#pragma unroll
    for (int j = 0; j < 4; ++j) {
      const int rb = wc * 64 + j * 16 + rl;
      bf[j] = *(const f16x8*)(Bb + rb * 32 + ((g ^ ((rb >> 1) & 3)) * 8));
    }
    __builtin_amdgcn_s_setprio(1);
#pragma unroll
    for (int i = 0; i < 4; ++i)
#pragma unroll
      for (int j = 0; j < 4; ++j)
        acc[i][j] = mfma16(af[i], bf[j], acc[i][j]);
    __builtin_amdgcn_s_setprio(0);
    __builtin_amdgcn_sched_barrier(0);

    c = (c == 2) ? 0 : c + 1;
    cs = (cs == 2) ? 0 : cs + 1;
  }

#pragma unroll
  for (int i = 0; i < 4; ++i)
#pragma unroll
    for (int j = 0; j < 4; ++j)
#pragma unroll
      for (int r = 0; r < 4; ++r) {
        int m = bm + wr * 64 + i * 16 + g * 4 + r;
        int n = bn + wc * 64 + j * 16 + rl;
        out[(size_t)m * 1024 + n] = acc[i][j][r] + bias[n];
      }
}

// ---------------- flash attention v2.1 (unchanged from round 3) ----------------
__global__ __launch_bounds__(256, 4) void k_attn2(
    const f16* __restrict__ q, const f16* __restrict__ kgl,
    const f16* __restrict__ vt, f16* __restrict__ o) {
  constexpr int S = 2048;
  __shared__ __align__(16) f16 Ks[2][64 * 64];
  __shared__ __align__(16) f16 Vs[2][64 * 64];
  __shared__ __align__(16) f16 Ps[4][16 * 64];

  const int blk = blockIdx.x;
  const int sidx = blk >> 3;
  const int bh = (blk & 7) * 8 + (sidx & 7);
  const int qb = 15 - (sidx >> 3);

  const int t = threadIdx.x, lane = t & 63, w = t >> 6;
  const int g = lane >> 4, rl = lane & 15;

  const f16* qp = q + ((size_t)bh * S + qb * 128) * 64;
  const f16* kb = kgl + (size_t)bh * S * 64;
  const f16* vb = vt + (size_t)bh * 64 * S;

  f16x8 qf[2][2];
#pragma unroll
  for (int sub = 0; sub < 2; ++sub)
#pragma unroll
    for (int ks = 0; ks < 2; ++ks)
      qf[sub][ks] = *(const f16x8*)(qp + (size_t)(w * 32 + sub * 16 + rl) * 64 + ks * 32 + g * 8);

  f32x4 oacc[2][4] = {};
  float lrow[2] = {0.f, 0.f};

  const int srow = lane >> 3;
  const int sslot = (lane & 7) ^ srow;

  const int nkt = 2 * qb + 2;
  const int qmaxw = qb * 128 + w * 32 + 31;

  auto STAGE = [&](int bufi, int kt) {
#pragma unroll
    for (int i = 0; i < 2; ++i) {
      const int r0 = w * 16 + i * 8;
      gl_lds16(kb + (size_t)(kt * 64 + r0 + srow) * 64 + sslot * 8, &Ks[bufi][r0 * 64]);
      gl_lds16(vb + (size_t)(r0 + srow) * S + kt * 64 + sslot * 8, &Vs[bufi][r0 * 64]);
    }
  };

  STAGE(0, 0);
  __syncthreads();
  int buf = 0;

  for (int kt = 0; kt < nkt; ++kt) {
    if (kt + 1 < nkt) STAGE(buf ^ 1, kt + 1);

    if (kt * 64 <= qmaxw) {
      const f16* Kb = &Ks[buf][0];
      const f16* Vb = &Vs[buf][0];
#pragma unroll
      for (int sub = 0; sub < 2; ++sub) {
        const int qsub = qb * 128 + w * 32 + sub * 16;
        if (kt * 64 > qsub + 15) continue;

        f32x4 sT[4] = {};
#pragma unroll
        for (int j = 0; j < 4; ++j)
#pragma unroll
          for (int ks = 0; ks < 2; ++ks) {
            int row = j * 16 + rl;
            f16x8 kf = *(const f16x8*)(Kb + row * 64 + (((ks * 4 + g) ^ (rl & 7)) * 8));
            sT[j] = mfma16(kf, qf[sub][ks], sT[j]);
          }

        if (kt * 64 + 63 > qsub) {
#pragma unroll
          for (int j = 0; j < 4; ++j)
#pragma unroll
            for (int r = 0; r < 4; ++r)
              if (kt * 64 + j * 16 + g * 4 + r > qsub + rl) sT[j][r] = -1e30f;
        }

        float ps = 0.f;
#pragma unroll
        for (int j = 0; j < 4; ++j) {
          f16x4 pb;
#pragma unroll
          for (int r = 0; r < 4; ++r) {
            float p = exp2f(sT[j][r]);
            ps += p;
            pb[r] = (f16)p;
          }
          *(f16x4*)(&Ps[w][0] + rl * 64 + (((j * 2 + (g >> 1)) ^ (rl & 7)) * 8) + (g & 1) * 4) = pb;
        }
        lrow[sub] += ps;

        asm volatile("s_waitcnt lgkmcnt(0)" ::: "memory");
        __builtin_amdgcn_sched_barrier(0);

        f16x8 pf[2];
#pragma unroll
        for (int ks = 0; ks < 2; ++ks)
          pf[ks] = *(const f16x8*)(&Ps[w][0] + rl * 64 + (((ks * 4 + g) ^ (rl & 7)) * 8));

#pragma unroll
        for (int dj = 0; dj < 4; ++dj)
#pragma unroll
          for (int ks = 0; ks < 2; ++ks) {
            int vrow = dj * 16 + rl;
            f16x8 vf = *(const f16x8*)(Vb + vrow * 64 + (((ks * 4 + g) ^ (rl & 7)) * 8));
            oacc[sub][dj] = mfma16(pf[ks], vf, oacc[sub][dj]);
          }
      }
    }
    __syncthreads();
    buf ^= 1;
  }

  float rinv[2];
#pragma unroll
  for (int sub = 0; sub < 2; ++sub) {
    float s_ = lrow[sub];
    s_ += __shfl_xor(s_, 16, 64);
    s_ += __shfl_xor(s_, 32, 64);
    rinv[sub] = 1.0f / s_;
  }

  const int h = bh & 15;
  const size_t rowb = (size_t)(bh >> 4) * 2048 + qb * 128 + w * 32;
#pragma unroll
  for (int sub = 0; sub < 2; ++sub)
#pragma unroll
    for (int r = 0; r < 4; ++r) {
      float ri = __shfl(rinv[sub], g * 4 + r, 64);
#pragma unroll
      for (int dj = 0; dj < 4; ++dj)
        o[(rowb + sub * 16 + g * 4 + r) * 1024 + h * 64 + dj * 16 + rl] =
            (f16)(oacc[sub][dj][r] * ri);
    }
}

extern "C" void kernel_launch(void* const* d_in, const int* in_sizes, int n_in,
                              void* d_out, int out_size, void* d_ws, size_t ws_size,
                              hipStream_t stream) {
  (void)in_sizes; (void)n_in; (void)out_size; (void)ws_size;
  const float* x    = (const float*)d_in[0];
  const float* wqkv = (const float*)d_in[1];
  const float* bqkv = (const float*)d_in[2];
  const float* wo   = (const float*)d_in[3];
  const float* bo   = (const float*)d_in[4];
  float* out = (float*)d_out;
  char* ws = (char*)d_ws;

  f16* xb    = (f16*)(ws + 0);          // x as f16 [8192][1024]
  f16* wqkvt = (f16*)(ws + 16777216);   // qkv_w^T f16 [3072][1024]
  f16* wot   = (f16*)(ws + 23068672);   // out_w^T f16 [1024][1024]
  f16* qws   = (f16*)(ws + 25165824);   // Q  [64][2048][64] (pre-scaled 0.125*log2e)
  f16* kws   = (f16*)(ws + 41943040);   // K  [64][2048][64]
  f16* vtws  = (f16*)(ws + 58720256);   // V^T[64][64][2048]
  f16* attnb = xb;                      // attn output reuses xb

  k_cvt<<<2048, 256, 0, stream>>>(x, xb, 8388608 / 4);
  k_tconv<<<dim3(96, 32), dim3(32, 8), 0, stream>>>(wqkv, wqkvt, 1024, 3072);
  k_tconv<<<dim3(32, 32), dim3(32, 8), 0, stream>>>(wo, wot, 1024, 1024);
  k_gemm_qkv2<<<dim3(12, 64), 512, 0, stream>>>(xb, wqkvt, bqkv, qws, kws, vtws);
  k_attn2<<<1024, 256, 0, stream>>>(qws, kws, vtws, attnb);
  k_gemm_out2<<<dim3(4, 64), 512, 0, stream>>>(attnb, wot, bo, out);
}

// Round 5
// 203.927 us; speedup vs baseline: 1.0021x; 1.0021x over previous
//
#include <hip/hip_runtime.h>

typedef unsigned int u32;
typedef _Float16 f16;
typedef _Float16 f16x8 __attribute__((ext_vector_type(8)));
typedef _Float16 f16x4 __attribute__((ext_vector_type(4)));
typedef float f32x4 __attribute__((ext_vector_type(4)));

#define LOG2E 1.4426950408889634f

__device__ __forceinline__ void gl_lds16(const void* g, void* l) {
  // async global->LDS, 16B per lane; LDS dest = wave-uniform base + lane*16
  __builtin_amdgcn_global_load_lds(
      (const __attribute__((address_space(1))) u32*)g,
      (__attribute__((address_space(3))) u32*)l, 16, 0, 0);
}

__device__ __forceinline__ f32x4 mfma16(f16x8 a, f16x8 b, f32x4 c) {
  return __builtin_amdgcn_mfma_f32_16x16x32_f16(a, b, c, 0, 0, 0);
}

// ---------------- fp32 -> fp16 convert (vectorized) ----------------
__global__ void k_cvt(const float* __restrict__ in, f16* __restrict__ out, int n4) {
  int stride = gridDim.x * blockDim.x;
  for (int i = blockIdx.x * blockDim.x + threadIdx.x; i < n4; i += stride) {
    f32x4 v = *(const f32x4*)(in + (size_t)i * 4);
    f16x4 o;
    o[0] = (f16)v[0]; o[1] = (f16)v[1]; o[2] = (f16)v[2]; o[3] = (f16)v[3];
    *(f16x4*)(out + (size_t)i * 4) = o;
  }
}

// ------------- transpose + convert: in fp32 [R][C] -> out f16 [C][R] -------------
__global__ void k_tconv(const float* __restrict__ in, f16* __restrict__ out, int R, int C) {
  __shared__ f16 tile[32][33];
  int c0 = blockIdx.x * 32, r0 = blockIdx.y * 32;
  int tx = threadIdx.x, ty = threadIdx.y;
#pragma unroll
  for (int i = ty; i < 32; i += 8)
    tile[i][tx] = (f16)in[(size_t)(r0 + i) * C + c0 + tx];
  __syncthreads();
#pragma unroll
  for (int i = ty; i < 32; i += 8)
    out[(size_t)(c0 + i) * R + r0 + tx] = tile[tx][i];
}

// ================= phase-interleaved GEMM core =================
// BM=256 BN=128 BK=64, 512 threads (8 waves 4Mx2N), per-wave 64x64 out.
// 3 LDS buffers (K-tile granularity, 48KB each); K-tile = 2 phases of
// {ds_read -> stage -> barrier -> lgkmcnt(0) -> 16 MFMA -> barrier};
// during tile kt stage tile kt+2 into buf (kt+2)%3 (free since kt-1);
// single vmcnt(6) per K-tile before its last barrier (6 loads = tile kt+2
// stay in flight; never drains to 0 mid-loop).
// LDS f16 layout: A plane(b,ks)= b*16384+ks*8192 : [256 rows][4 slots x 8]
// slot swizzled by (row>>1)&3 ; B plane(b,ks)= 49152+b*8192+ks*4096 : [128][32].

__device__ __forceinline__ void gemm_core(
    const f16* __restrict__ A, const f16* __restrict__ Bt,
    int bm, int bn, f16* SM, int w, int lane, f32x4 (&acc)[4][4]) {
  constexpr int KT = 16;  // K=1024 / BK=64
  const int g = lane >> 4, rl = lane & 15;
  const int l4 = lane >> 2, ls = lane & 3;
  const int wr = w >> 1, wc = w & 1;

  // staging sources (pre-swizzled cols so linear LDS dest + swizzled read agree)
  const int cr0 = w * 32 + l4, cr1 = cr0 + 16, br = w * 16 + l4;
  const f16* aS0 = A + (size_t)(bm + cr0) * 1024 + ((ls ^ ((cr0 >> 1) & 3)) * 8);
  const f16* aS1 = A + (size_t)(bm + cr1) * 1024 + ((ls ^ ((cr1 >> 1) & 3)) * 8);
  const f16* bS  = Bt + (size_t)(bn + br) * 1024 + ((ls ^ ((br >> 1) & 3)) * 8);

#define STG_A(b, ks, kt) do { \
    gl_lds16(aS0 + (kt) * 64 + (ks) * 32, SM + (b) * 16384 + (ks) * 8192 + (w * 2 + 0) * 512); \
    gl_lds16(aS1 + (kt) * 64 + (ks) * 32, SM + (b) * 16384 + (ks) * 8192 + (w * 2 + 1) * 512); } while (0)
#define STG_B(b, ks, kt) \
    gl_lds16(bS + (kt) * 64 + (ks) * 32, SM + 49152 + (b) * 8192 + (ks) * 4096 + w * 512)

  // prologue: tile0 -> buf0, tile1 -> buf1 (6 loads each, tile-ordered)
  STG_A(0, 0, 0); STG_B(0, 0, 0); STG_A(0, 1, 0); STG_B(0, 1, 0);
  STG_A(1, 0, 1); STG_B(1, 0, 1); STG_A(1, 1, 1); STG_B(1, 1, 1);
  asm volatile("s_waitcnt vmcnt(6)" ::: "memory");  // tile0 landed, tile1 in flight
  __builtin_amdgcn_s_barrier();

  int c = 0, cs = 2;
#pragma unroll 1
  for (int kt = 0; kt < KT; ++kt) {
    const f16* Ab = SM + c * 16384;
    const f16* Bb = SM + 49152 + c * 8192;
    const bool stg = (kt + 2 < KT);
    f16x8 bf[4][2];

    // ---------- phase 0 (m-quad 0) ----------
    {
#pragma unroll
      for (int j = 0; j < 4; ++j)
#pragma unroll
        for (int ks = 0; ks < 2; ++ks) {
          const int rb = wc * 64 + j * 16 + rl;
          bf[j][ks] = *(const f16x8*)(Bb + ks * 4096 + rb * 32 + ((g ^ ((rb >> 1) & 3)) * 8));
        }
      f16x8 af[2][2];
#pragma unroll
      for (int mi = 0; mi < 2; ++mi)
#pragma unroll
        for (int ks = 0; ks < 2; ++ks) {
          const int ra = wr * 64 + mi * 16 + rl;
          af[mi][ks] = *(const f16x8*)(Ab + ks * 8192 + ra * 32 + ((g ^ ((ra >> 1) & 3)) * 8));
        }
      if (stg) { STG_A(cs, 0, kt + 2); STG_B(cs, 0, kt + 2); }
      __builtin_amdgcn_s_barrier();
      asm volatile("s_waitcnt lgkmcnt(0)" ::: "memory");
      __builtin_amdgcn_sched_barrier(0);
      __builtin_amdgcn_s_setprio(1);
#pragma unroll
      for (int mi = 0; mi < 2; ++mi)
#pragma unroll
        for (int j = 0; j < 4; ++j) {
          acc[mi][j] = mfma16(af[mi][0], bf[j][0], acc[mi][j]);
          acc[mi][j] = mfma16(af[mi][1], bf[j][1], acc[mi][j]);
        }
      __builtin_amdgcn_s_setprio(0);
      __builtin_amdgcn_sched_barrier(0);
      __builtin_amdgcn_s_barrier();
    }

    // ---------- phase 1 (m-quad 1) ----------
    {
      f16x8 af[2][2];
#pragma unroll
      for (int mi = 0; mi < 2; ++mi)
#pragma unroll
        for (int ks = 0; ks < 2; ++ks) {
          const int ra = wr * 64 + (2 + mi) * 16 + rl;
          af[mi][ks] = *(const f16x8*)(Ab + ks * 8192 + ra * 32 + ((g ^ ((ra >> 1) & 3)) * 8));
        }
      if (stg) { STG_A(cs, 1, kt + 2); STG_B(cs, 1, kt + 2); }
      __builtin_amdgcn_s_barrier();
      asm volatile("s_waitcnt lgkmcnt(0)" ::: "memory");
      __builtin_amdgcn_sched_barrier(0);
      __builtin_amdgcn_s_setprio(1);
#pragma unroll
      for (int mi = 0; mi < 2; ++mi)
#pragma unroll
        for (int j = 0; j < 4; ++j) {
          acc[2 + mi][j] = mfma16(af[mi][0], bf[j][0], acc[2 + mi][j]);
          acc[2 + mi][j] = mfma16(af[mi][1], bf[j][1], acc[2 + mi][j]);
        }
      __builtin_amdgcn_s_setprio(0);
      __builtin_amdgcn_sched_barrier(0);
      // gate for tile kt+1 (its 6 loads staged during kt-1); kt+2's 6 in flight
      if (kt + 2 < KT)      { asm volatile("s_waitcnt vmcnt(6)" ::: "memory"); }
      else if (kt + 1 < KT) { asm volatile("s_waitcnt vmcnt(0)" ::: "memory"); }
      __builtin_amdgcn_s_barrier();
    }

    c = (c == 2) ? 0 : c + 1;
    cs = (cs == 2) ? 0 : cs + 1;
  }
#undef STG_A
#undef STG_B
}

// ---------------- QKV projection GEMM (8-phase-style) ----------------
__global__ __launch_bounds__(512, 2) void k_gemm_qkv3(
    const f16* __restrict__ A, const f16* __restrict__ Bt,
    const float* __restrict__ bias,
    f16* __restrict__ qo, f16* __restrict__ ko2, f16* __restrict__ vto) {
  __shared__ __align__(16) f16 SM[73728];  // 144 KB
  const int lin0 = blockIdx.y * 24 + blockIdx.x;       // 768 blocks
  const int lin = (lin0 & 7) * 96 + (lin0 >> 3);       // XCD-contiguous remap
  const int bn = (lin % 24) * 128, bm = (lin / 24) * 256;
  const int t = threadIdx.x, lane = t & 63, w = t >> 6;
  const int g = lane >> 4, rl = lane & 15;
  const int wr = w >> 1, wc = w & 1;

  f32x4 acc[4][4] = {};
  gemm_core(A, Bt, bm, bn, SM, w, lane, acc);

  // epilogue: C row=(lane>>4)*4+reg, col=lane&15; scatter q/k/v
#pragma unroll
  for (int i = 0; i < 4; ++i)
#pragma unroll
    for (int j = 0; j < 4; ++j)
#pragma unroll
      for (int r = 0; r < 4; ++r) {
        int m = bm + wr * 64 + i * 16 + g * 4 + r;
        int n = bn + wc * 64 + j * 16 + rl;
        float v = acc[i][j][r] + bias[n];
        int b = m >> 11, s = m & 2047;
        int h = n / 192, rem = n - h * 192;
        int tsel = rem >> 6, d = rem & 63;
        size_t bh = (size_t)(b * 16 + h);
        if (tsel == 0)      qo[(bh * 2048 + s) * 64 + d] = (f16)(v * (0.125f * LOG2E));
        else if (tsel == 1) ko2[(bh * 2048 + s) * 64 + d] = (f16)v;
        else                vto[(bh * 64 + d) * 2048 + s] = (f16)v;  // V transposed
      }
}

// ---------------- output projection GEMM (8-phase-style) ----------------
__global__ __launch_bounds__(512, 2) void k_gemm_out3(
    const f16* __restrict__ A, const f16* __restrict__ Bt,
    const float* __restrict__ bias, float* __restrict__ out) {
  __shared__ __align__(16) f16 SM[73728];
  const int lin0 = blockIdx.y * 8 + blockIdx.x;        // 256 blocks
  const int lin = (lin0 & 7) * 32 + (lin0 >> 3);
  const int bn = (lin % 8) * 128, bm = (lin / 8) * 256;
  const int t = threadIdx.x, lane = t & 63, w = t >> 6;
  const int g = lane >> 4, rl = lane & 15;
  const int wr = w >> 1, wc = w & 1;

  f32x4 acc[4][4] = {};
  gemm_core(A, Bt, bm, bn, SM, w, lane, acc);

#pragma unroll
  for (int i = 0; i < 4; ++i)
#pragma unroll
    for (int j = 0; j < 4; ++j)
#pragma unroll
      for (int r = 0; r < 4; ++r) {
        int m = bm + wr * 64 + i * 16 + g * 4 + r;
        int n = bn + wc * 64 + j * 16 + rl;
        out[(size_t)m * 1024 + n] = acc[i][j][r] + bias[n];
      }
}

// ---------------- flash attention v2.1 (unchanged) ----------------
__global__ __launch_bounds__(256, 4) void k_attn2(
    const f16* __restrict__ q, const f16* __restrict__ kgl,
    const f16* __restrict__ vt, f16* __restrict__ o) {
  constexpr int S = 2048;
  __shared__ __align__(16) f16 Ks[2][64 * 64];
  __shared__ __align__(16) f16 Vs[2][64 * 64];
  __shared__ __align__(16) f16 Ps[4][16 * 64];

  const int blk = blockIdx.x;
  const int sidx = blk >> 3;
  const int bh = (blk & 7) * 8 + (sidx & 7);
  const int qb = 15 - (sidx >> 3);

  const int t = threadIdx.x, lane = t & 63, w = t >> 6;
  const int g = lane >> 4, rl = lane & 15;

  const f16* qp = q + ((size_t)bh * S + qb * 128) * 64;
  const f16* kb = kgl + (size_t)bh * S * 64;
  const f16* vb = vt + (size_t)bh * 64 * S;

  f16x8 qf[2][2];
#pragma unroll
  for (int sub = 0; sub < 2; ++sub)
#pragma unroll
    for (int ks = 0; ks < 2; ++ks)
      qf[sub][ks] = *(const f16x8*)(qp + (size_t)(w * 32 + sub * 16 + rl) * 64 + ks * 32 + g * 8);

  f32x4 oacc[2][4] = {};
  float lrow[2] = {0.f, 0.f};

  const int srow = lane >> 3;
  const int sslot = (lane & 7) ^ srow;

  const int nkt = 2 * qb + 2;
  const int qmaxw = qb * 128 + w * 32 + 31;

  auto STAGE = [&](int bufi, int kt) {
#pragma unroll
    for (int i = 0; i < 2; ++i) {
      const int r0 = w * 16 + i * 8;
      gl_lds16(kb + (size_t)(kt * 64 + r0 + srow) * 64 + sslot * 8, &Ks[bufi][r0 * 64]);
      gl_lds16(vb + (size_t)(r0 + srow) * S + kt * 64 + sslot * 8, &Vs[bufi][r0 * 64]);
    }
  };

  STAGE(0, 0);
  __syncthreads();
  int buf = 0;

  for (int kt = 0; kt < nkt; ++kt) {
    if (kt + 1 < nkt) STAGE(buf ^ 1, kt + 1);

    if (kt * 64 <= qmaxw) {
      const f16* Kb = &Ks[buf][0];
      const f16* Vb = &Vs[buf][0];
#pragma unroll
      for (int sub = 0; sub < 2; ++sub) {
        const int qsub = qb * 128 + w * 32 + sub * 16;
        if (kt * 64 > qsub + 15) continue;

        f32x4 sT[4] = {};
#pragma unroll
        for (int j = 0; j < 4; ++j)
#pragma unroll
          for (int ks = 0; ks < 2; ++ks) {
            int row = j * 16 + rl;
            f16x8 kf = *(const f16x8*)(Kb + row * 64 + (((ks * 4 + g) ^ (rl & 7)) * 8));
            sT[j] = mfma16(kf, qf[sub][ks], sT[j]);
          }

        if (kt * 64 + 63 > qsub) {
#pragma unroll
          for (int j = 0; j < 4; ++j)
#pragma unroll
            for (int r = 0; r < 4; ++r)
              if (kt * 64 + j * 16 + g * 4 + r > qsub + rl) sT[j][r] = -1e30f;
        }

        float ps = 0.f;
#pragma unroll
        for (int j = 0; j < 4; ++j) {
          f16x4 pb;
#pragma unroll
          for (int r = 0; r < 4; ++r) {
            float p = exp2f(sT[j][r]);
            ps += p;
            pb[r] = (f16)p;
          }
          *(f16x4*)(&Ps[w][0] + rl * 64 + (((j * 2 + (g >> 1)) ^ (rl & 7)) * 8) + (g & 1) * 4) = pb;
        }
        lrow[sub] += ps;

        asm volatile("s_waitcnt lgkmcnt(0)" ::: "memory");
        __builtin_amdgcn_sched_barrier(0);

        f16x8 pf[2];
#pragma unroll
        for (int ks = 0; ks < 2; ++ks)
          pf[ks] = *(const f16x8*)(&Ps[w][0] + rl * 64 + (((ks * 4 + g) ^ (rl & 7)) * 8));

#pragma unroll
        for (int dj = 0; dj < 4; ++dj)
#pragma unroll
          for (int ks = 0; ks < 2; ++ks) {
            int vrow = dj * 16 + rl;
            f16x8 vf = *(const f16x8*)(Vb + vrow * 64 + (((ks * 4 + g) ^ (rl & 7)) * 8));
            oacc[sub][dj] = mfma16(pf[ks], vf, oacc[sub][dj]);
          }
      }
    }
    __syncthreads();
    buf ^= 1;
  }

  float rinv[2];
#pragma unroll
  for (int sub = 0; sub < 2; ++sub) {
    float s_ = lrow[sub];
    s_ += __shfl_xor(s_, 16, 64);
    s_ += __shfl_xor(s_, 32, 64);
    rinv[sub] = 1.0f / s_;
  }

  const int h = bh & 15;
  const size_t rowb = (size_t)(bh >> 4) * 2048 + qb * 128 + w * 32;
#pragma unroll
  for (int sub = 0; sub < 2; ++sub)
#pragma unroll
    for (int r = 0; r < 4; ++r) {
      float ri = __shfl(rinv[sub], g * 4 + r, 64);
#pragma unroll
      for (int dj = 0; dj < 4; ++dj)
        o[(rowb + sub * 16 + g * 4 + r) * 1024 + h * 64 + dj * 16 + rl] =
            (f16)(oacc[sub][dj][r] * ri);
    }
}

extern "C" void kernel_launch(void* const* d_in, const int* in_sizes, int n_in,
                              void* d_out, int out_size, void* d_ws, size_t ws_size,
                              hipStream_t stream) {
  (void)in_sizes; (void)n_in; (void)out_size; (void)ws_size;
  const float* x    = (const float*)d_in[0];
  const float* wqkv = (const float*)d_in[1];
  const float* bqkv = (const float*)d_in[2];
  const float* wo   = (const float*)d_in[3];
  const float* bo   = (const float*)d_in[4];
  float* out = (float*)d_out;
  char* ws = (char*)d_ws;

  f16* xb    = (f16*)(ws + 0);          // x as f16 [8192][1024]
  f16* wqkvt = (f16*)(ws + 16777216);   // qkv_w^T f16 [3072][1024]
  f16* wot   = (f16*)(ws + 23068672);   // out_w^T f16 [1024][1024]
  f16* qws   = (f16*)(ws + 25165824);   // Q  [64][2048][64] (pre-scaled 0.125*log2e)
  f16* kws   = (f16*)(ws + 41943040);   // K  [64][2048][64]
  f16* vtws  = (f16*)(ws + 58720256);   // V^T[64][64][2048]
  f16* attnb = xb;                      // attn output reuses xb

  k_cvt<<<2048, 256, 0, stream>>>(x, xb, 8388608 / 4);
  k_tconv<<<dim3(96, 32), dim3(32, 8), 0, stream>>>(wqkv, wqkvt, 1024, 3072);
  k_tconv<<<dim3(32, 32), dim3(32, 8), 0, stream>>>(wo, wot, 1024, 1024);
  k_gemm_qkv3<<<dim3(24, 32), 512, 0, stream>>>(xb, wqkvt, bqkv, qws, kws, vtws);
  k_attn2<<<1024, 256, 0, stream>>>(qws, kws, vtws, attnb);
  k_gemm_out3<<<dim3(8, 32), 512, 0, stream>>>(attnb, wot, bo, out);
}

// Round 6
// 191.197 us; speedup vs baseline: 1.0688x; 1.0666x over previous
//
#include <hip/hip_runtime.h>

typedef unsigned int u32;
typedef _Float16 f16;
typedef _Float16 f16x8 __attribute__((ext_vector_type(8)));
typedef _Float16 f16x4 __attribute__((ext_vector_type(4)));
typedef float f32x4 __attribute__((ext_vector_type(4)));

#define LOG2E 1.4426950408889634f

__device__ __forceinline__ void gl_lds16(const void* g, void* l) {
  // async global->LDS, 16B per lane; LDS dest = wave-uniform base + lane*16
  __builtin_amdgcn_global_load_lds(
      (const __attribute__((address_space(1))) u32*)g,
      (__attribute__((address_space(3))) u32*)l, 16, 0, 0);
}

__device__ __forceinline__ f32x4 mfma16(f16x8 a, f16x8 b, f32x4 c) {
  return __builtin_amdgcn_mfma_f32_16x16x32_f16(a, b, c, 0, 0, 0);
}

// ---------------- fp32 -> fp16 convert (vectorized) ----------------
__global__ void k_cvt(const float* __restrict__ in, f16* __restrict__ out, int n4) {
  int stride = gridDim.x * blockDim.x;
  for (int i = blockIdx.x * blockDim.x + threadIdx.x; i < n4; i += stride) {
    f32x4 v = *(const f32x4*)(in + (size_t)i * 4);
    f16x4 o;
    o[0] = (f16)v[0]; o[1] = (f16)v[1]; o[2] = (f16)v[2]; o[3] = (f16)v[3];
    *(f16x4*)(out + (size_t)i * 4) = o;
  }
}

// ------------- transpose + convert: in fp32 [R][C] -> out f16 [C][R] -------------
__global__ void k_tconv(const float* __restrict__ in, f16* __restrict__ out, int R, int C) {
  __shared__ f16 tile[32][33];
  int c0 = blockIdx.x * 32, r0 = blockIdx.y * 32;
  int tx = threadIdx.x, ty = threadIdx.y;
#pragma unroll
  for (int i = ty; i < 32; i += 8)
    tile[i][tx] = (f16)in[(size_t)(r0 + i) * C + c0 + tx];
  __syncthreads();
#pragma unroll
  for (int i = ty; i < 32; i += 8)
    out[(size_t)(c0 + i) * R + r0 + tx] = tile[tx][i];
}

// ================= fat-wave pipelined GEMM core =================
// Block 128x256, 4 waves (1M x 4N), per-wave 128x64 (acc[8][4]), BK=32.
// LDS demand: operand reads 3378*(128+64)/8192 = 79 B/cyc + 20 staging writes
// (vs 126 at 64x64-wave) -> under the ~85 B/cyc ds_read_b128 supply.
// 3 buffers x 24KB = 72KB -> 2 blocks/CU resident.
// K-tile = 2 phases {ds_read; stage 3 gl_lds; barrier; lgkmcnt(0); 16 MFMA; barrier};
// stage tile kt+2 during kt; single vmcnt(6) gate at tile end (tile kt+1 landed,
// kt+2's 6 loads stay in flight - never drains mid-loop).
__device__ __forceinline__ void gemm_fat(
    const f16* __restrict__ A, const f16* __restrict__ Bt,
    int bm, int bn, f16* SM, int w, int lane, f32x4 (&acc)[8][4]) {
  constexpr int KT = 32;  // K=1024 / BK=32
  const int g = lane >> 4, rl = lane & 15;
  const int l4 = lane >> 2, ls = lane & 3;
  const int sslot = ls ^ ((l4 >> 1) & 3);  // pre-swizzled source 16B-slot

  // staging: A rows w*32+l4 (+16 for instr1); B rows j*64 + w*16 + l4
  const f16* aS = A + (size_t)(bm + w * 32 + l4) * 1024 + sslot * 8;
  const f16* bS = Bt + (size_t)(bn + w * 16 + l4) * 1024 + sslot * 8;
  f16* aD = SM + w * 1024;        // + i*512 + buf*12288
  f16* bD = SM + 4096 + w * 512;  // + j*2048 + buf*12288

#define STGH0(b, kt) do { \
    gl_lds16(aS + (kt) * 32,          aD + (b) * 12288); \
    gl_lds16(aS + 16384 + (kt) * 32,  aD + (b) * 12288 + 512); \
    gl_lds16(bS + (kt) * 32,          bD + (b) * 12288); } while (0)
#define STGH1(b, kt) do { \
    gl_lds16(bS + 65536 + (kt) * 32,  bD + (b) * 12288 + 2048); \
    gl_lds16(bS + 131072 + (kt) * 32, bD + (b) * 12288 + 4096); \
    gl_lds16(bS + 196608 + (kt) * 32, bD + (b) * 12288 + 6144); } while (0)

  // prologue: tile0 -> buf0, tile1 -> buf1 (FIFO: 6 loads per tile, tile-ordered)
  STGH0(0, 0); STGH1(0, 0);
  STGH0(1, 1); STGH1(1, 1);
  asm volatile("s_waitcnt vmcnt(6)" ::: "memory");  // tile0 landed, tile1 in flight
  __builtin_amdgcn_s_barrier();

  const int ro = rl * 32 + ((g ^ ((rl >> 1) & 3)) * 8);

  int c = 0, cs = 2;
#pragma unroll 1
  for (int kt = 0; kt < KT; ++kt) {
    const f16* SMc = SM + c * 12288;
    const bool stg = (kt + 2 < KT);
    f16x8 bf[4], af[4];

    // ---------- phase 0: M rows 0..63 ----------
    {
#pragma unroll
      for (int j = 0; j < 4; ++j)
        bf[j] = *(const f16x8*)(SMc + 4096 + w * 2048 + j * 512 + ro);
#pragma unroll
      for (int mi = 0; mi < 4; ++mi)
        af[mi] = *(const f16x8*)(SMc + mi * 512 + ro);
      if (stg) STGH0(cs, kt + 2);
      __builtin_amdgcn_s_barrier();
      asm volatile("s_waitcnt lgkmcnt(0)" ::: "memory");
      __builtin_amdgcn_sched_barrier(0);
      __builtin_amdgcn_s_setprio(1);
#pragma unroll
      for (int mi = 0; mi < 4; ++mi)
#pragma unroll
        for (int j = 0; j < 4; ++j)
          acc[mi][j] = mfma16(af[mi], bf[j], acc[mi][j]);
      __builtin_amdgcn_s_setprio(0);
      __builtin_amdgcn_sched_barrier(0);
      __builtin_amdgcn_s_barrier();
    }

    // ---------- phase 1: M rows 64..127 ----------
    {
#pragma unroll
      for (int mi = 0; mi < 4; ++mi)
        af[mi] = *(const f16x8*)(SMc + (4 + mi) * 512 + ro);
      if (stg) STGH1(cs, kt + 2);
      __builtin_amdgcn_s_barrier();
      asm volatile("s_waitcnt lgkmcnt(0)" ::: "memory");
      __builtin_amdgcn_sched_barrier(0);
      __builtin_amdgcn_s_setprio(1);
#pragma unroll
      for (int mi = 0; mi < 4; ++mi)
#pragma unroll
        for (int j = 0; j < 4; ++j)
          acc[4 + mi][j] = mfma16(af[mi], bf[j], acc[4 + mi][j]);
      __builtin_amdgcn_s_setprio(0);
      __builtin_amdgcn_sched_barrier(0);
      // gate: tile kt+1's 6 loads landed; kt+2's 6 remain in flight
      if (kt + 2 < KT)      { asm volatile("s_waitcnt vmcnt(6)" ::: "memory"); }
      else if (kt + 1 < KT) { asm volatile("s_waitcnt vmcnt(0)" ::: "memory"); }
      __builtin_amdgcn_s_barrier();
      __builtin_amdgcn_sched_barrier(0);
    }

    c = (c == 2) ? 0 : c + 1;
    cs = (cs == 2) ? 0 : cs + 1;
  }
#undef STGH0
#undef STGH1
}

// ---------------- QKV projection GEMM (fat-wave) ----------------
__global__ __launch_bounds__(256, 2) void k_gemm_qkv4(
    const f16* __restrict__ A, const f16* __restrict__ Bt,
    const float* __restrict__ bias,
    f16* __restrict__ qo, f16* __restrict__ ko2, f16* __restrict__ vto) {
  __shared__ __align__(16) f16 SM[36864];  // 72 KB
  const int lin0 = blockIdx.y * 12 + blockIdx.x;   // 768 blocks
  const int lin = (lin0 & 7) * 96 + (lin0 >> 3);   // XCD-contiguous (768%8==0, bijective)
  const int bn = (lin % 12) * 256, bm = (lin / 12) * 128;
  const int t = threadIdx.x, lane = t & 63, w = t >> 6;
  const int g = lane >> 4, rl = lane & 15;

  f32x4 acc[8][4] = {};
  gemm_fat(A, Bt, bm, bn, SM, w, lane, acc);

  // epilogue: C row=(lane>>4)*4+reg (m), col=lane&15 (n); scatter q/k/v
#pragma unroll
  for (int mi = 0; mi < 8; ++mi)
#pragma unroll
    for (int j = 0; j < 4; ++j)
#pragma unroll
      for (int r = 0; r < 4; ++r) {
        int m = bm + mi * 16 + g * 4 + r;
        int n = bn + w * 64 + j * 16 + rl;
        float v = acc[mi][j][r] + bias[n];
        int b = m >> 11, s = m & 2047;
        int h = n / 192, rem = n - h * 192;
        int tsel = rem >> 6, d = rem & 63;
        size_t bh = (size_t)(b * 16 + h);
        if (tsel == 0)      qo[(bh * 2048 + s) * 64 + d] = (f16)(v * (0.125f * LOG2E));
        else if (tsel == 1) ko2[(bh * 2048 + s) * 64 + d] = (f16)v;
        else                vto[(bh * 64 + d) * 2048 + s] = (f16)v;  // V transposed
      }
}

// ---------------- output projection GEMM (fat-wave) ----------------
__global__ __launch_bounds__(256, 2) void k_gemm_out4(
    const f16* __restrict__ A, const f16* __restrict__ Bt,
    const float* __restrict__ bias, float* __restrict__ out) {
  __shared__ __align__(16) f16 SM[36864];
  const int lin0 = blockIdx.y * 4 + blockIdx.x;    // 256 blocks
  const int lin = (lin0 & 7) * 32 + (lin0 >> 3);
  const int bn = (lin % 4) * 256, bm = (lin / 4) * 128;
  const int t = threadIdx.x, lane = t & 63, w = t >> 6;
  const int g = lane >> 4, rl = lane & 15;

  f32x4 acc[8][4] = {};
  gemm_fat(A, Bt, bm, bn, SM, w, lane, acc);

#pragma unroll
  for (int mi = 0; mi < 8; ++mi)
#pragma unroll
    for (int j = 0; j < 4; ++j)
#pragma unroll
      for (int r = 0; r < 4; ++r) {
        int m = bm + mi * 16 + g * 4 + r;
        int n = bn + w * 64 + j * 16 + rl;
        out[(size_t)m * 1024 + n] = acc[mi][j][r] + bias[n];
      }
}

// ---------------- flash attention v2.1 (unchanged) ----------------
__global__ __launch_bounds__(256, 4) void k_attn2(
    const f16* __restrict__ q, const f16* __restrict__ kgl,
    const f16* __restrict__ vt, f16* __restrict__ o) {
  constexpr int S = 2048;
  __shared__ __align__(16) f16 Ks[2][64 * 64];
  __shared__ __align__(16) f16 Vs[2][64 * 64];
  __shared__ __align__(16) f16 Ps[4][16 * 64];

  const int blk = blockIdx.x;
  const int sidx = blk >> 3;
  const int bh = (blk & 7) * 8 + (sidx & 7);
  const int qb = 15 - (sidx >> 3);

  const int t = threadIdx.x, lane = t & 63, w = t >> 6;
  const int g = lane >> 4, rl = lane & 15;

  const f16* qp = q + ((size_t)bh * S + qb * 128) * 64;
  const f16* kb = kgl + (size_t)bh * S * 64;
  const f16* vb = vt + (size_t)bh * 64 * S;

  f16x8 qf[2][2];
#pragma unroll
  for (int sub = 0; sub < 2; ++sub)
#pragma unroll
    for (int ks = 0; ks < 2; ++ks)
      qf[sub][ks] = *(const f16x8*)(qp + (size_t)(w * 32 + sub * 16 + rl) * 64 + ks * 32 + g * 8);

  f32x4 oacc[2][4] = {};
  float lrow[2] = {0.f, 0.f};

  const int srow = lane >> 3;
  const int sslot = (lane & 7) ^ srow;

  const int nkt = 2 * qb + 2;
  const int qmaxw = qb * 128 + w * 32 + 31;

  auto STAGE = [&](int bufi, int kt) {
#pragma unroll
    for (int i = 0; i < 2; ++i) {
      const int r0 = w * 16 + i * 8;
      gl_lds16(kb + (size_t)(kt * 64 + r0 + srow) * 64 + sslot * 8, &Ks[bufi][r0 * 64]);
      gl_lds16(vb + (size_t)(r0 + srow) * S + kt * 64 + sslot * 8, &Vs[bufi][r0 * 64]);
    }
  };

  STAGE(0, 0);
  __syncthreads();
  int buf = 0;

  for (int kt = 0; kt < nkt; ++kt) {
    if (kt + 1 < nkt) STAGE(buf ^ 1, kt + 1);

    if (kt * 64 <= qmaxw) {
      const f16* Kb = &Ks[buf][0];
      const f16* Vb = &Vs[buf][0];
#pragma unroll
      for (int sub = 0; sub < 2; ++sub) {
        const int qsub = qb * 128 + w * 32 + sub * 16;
        if (kt * 64 > qsub + 15) continue;

        f32x4 sT[4] = {};
#pragma unroll
        for (int j = 0; j < 4; ++j)
#pragma unroll
          for (int ks = 0; ks < 2; ++ks) {
            int row = j * 16 + rl;
            f16x8 kf = *(const f16x8*)(Kb + row * 64 + (((ks * 4 + g) ^ (rl & 7)) * 8));
            sT[j] = mfma16(kf, qf[sub][ks], sT[j]);
          }

        if (kt * 64 + 63 > qsub) {
#pragma unroll
          for (int j = 0; j < 4; ++j)
#pragma unroll
            for (int r = 0; r < 4; ++r)
              if (kt * 64 + j * 16 + g * 4 + r > qsub + rl) sT[j][r] = -1e30f;
        }

        float ps = 0.f;
#pragma unroll
        for (int j = 0; j < 4; ++j) {
          f16x4 pb;
#pragma unroll
          for (int r = 0; r < 4; ++r) {
            float p = exp2f(sT[j][r]);
            ps += p;
            pb[r] = (f16)p;
          }
          *(f16x4*)(&Ps[w][0] + rl * 64 + (((j * 2 + (g >> 1)) ^ (rl & 7)) * 8) + (g & 1) * 4) = pb;
        }
        lrow[sub] += ps;

        asm volatile("s_waitcnt lgkmcnt(0)" ::: "memory");
        __builtin_amdgcn_sched_barrier(0);

        f16x8 pf[2];
#pragma unroll
        for (int ks = 0; ks < 2; ++ks)
          pf[ks] = *(const f16x8*)(&Ps[w][0] + rl * 64 + (((ks * 4 + g) ^ (rl & 7)) * 8));

#pragma unroll
        for (int dj = 0; dj < 4; ++dj)
#pragma unroll
          for (int ks = 0; ks < 2; ++ks) {
            int vrow = dj * 16 + rl;
            f16x8 vf = *(const f16x8*)(Vb + vrow * 64 + (((ks * 4 + g) ^ (rl & 7)) * 8));
            oacc[sub][dj] = mfma16(pf[ks], vf, oacc[sub][dj]);
          }
      }
    }
    __syncthreads();
    buf ^= 1;
  }

  float rinv[2];
#pragma unroll
  for (int sub = 0; sub < 2; ++sub) {
    float s_ = lrow[sub];
    s_ += __shfl_xor(s_, 16, 64);
    s_ += __shfl_xor(s_, 32, 64);
    rinv[sub] = 1.0f / s_;
  }

  const int h = bh & 15;
  const size_t rowb = (size_t)(bh >> 4) * 2048 + qb * 128 + w * 32;
#pragma unroll
  for (int sub = 0; sub < 2; ++sub)
#pragma unroll
    for (int r = 0; r < 4; ++r) {
      float ri = __shfl(rinv[sub], g * 4 + r, 64);
#pragma unroll
      for (int dj = 0; dj < 4; ++dj)
        o[(rowb + sub * 16 + g * 4 + r) * 1024 + h * 64 + dj * 16 + rl] =
            (f16)(oacc[sub][dj][r] * ri);
    }
}

extern "C" void kernel_launch(void* const* d_in, const int* in_sizes, int n_in,
                              void* d_out, int out_size, void* d_ws, size_t ws_size,
                              hipStream_t stream) {
  (void)in_sizes; (void)n_in; (void)out_size; (void)ws_size;
  const float* x    = (const float*)d_in[0];
  const float* wqkv = (const float*)d_in[1];
  const float* bqkv = (const float*)d_in[2];
  const float* wo   = (const float*)d_in[3];
  const float* bo   = (const float*)d_in[4];
  float* out = (float*)d_out;
  char* ws = (char*)d_ws;

  f16* xb    = (f16*)(ws + 0);          // x as f16 [8192][1024]
  f16* wqkvt = (f16*)(ws + 16777216);   // qkv_w^T f16 [3072][1024]
  f16* wot   = (f16*)(ws + 23068672);   // out_w^T f16 [1024][1024]
  f16* qws   = (f16*)(ws + 25165824);   // Q  [64][2048][64] (pre-scaled 0.125*log2e)
  f16* kws   = (f16*)(ws + 41943040);   // K  [64][2048][64]
  f16* vtws  = (f16*)(ws + 58720256);   // V^T[64][64][2048]
  f16* attnb = xb;                      // attn output reuses xb

  k_cvt<<<2048, 256, 0, stream>>>(x, xb, 8388608 / 4);
  k_tconv<<<dim3(96, 32), dim3(32, 8), 0, stream>>>(wqkv, wqkvt, 1024, 3072);
  k_tconv<<<dim3(32, 32), dim3(32, 8), 0, stream>>>(wo, wot, 1024, 1024);
  k_gemm_qkv4<<<dim3(12, 64), 256, 0, stream>>>(xb, wqkvt, bqkv, qws, kws, vtws);
  k_attn2<<<1024, 256, 0, stream>>>(qws, kws, vtws, attnb);
  k_gemm_out4<<<dim3(4, 64), 256, 0, stream>>>(attnb, wot, bo, out);
}